// Round 4
// baseline (516.521 us; speedup 1.0000x reference)
//
#include <hip/hip_runtime.h>
#include <stdint.h>

#define B_ROWS 8192
#define DIM 4096
#define E_CODES 512
#define MARGIN 16.0f

typedef __attribute__((ext_vector_type(8))) short short8;
typedef __attribute__((ext_vector_type(4))) float floatx4;
typedef __attribute__((ext_vector_type(4), aligned(4))) float f4u;  // unaligned-ok float4
typedef unsigned short ushort_t;

// ---- workspace layout (float units) ----
#define WS_P0     0                       // partial scores kh=0: 8192*512 floats (incl. ||e||^2)
#define WS_ENORM  4194304                 // 512 floats
#define WS_COUNTS 4194816                 // 512 ints
#define WS_LOSS   4195328                 // 1 float

// ---- output layout (float units) ----
#define O_LOSS 0
#define O_Q    1
#define O_PERP 33554433
#define O_ENC  33554434
// scratch carved out of the Q region (fully overwritten by k_quant afterwards):
#define O_XBF   4          // bf16 X (swizzled): [4, 16777220)
#define O_P1    16777224   // partial kh=1: [16777224, 20971528)
#define O_CBBF  20971528   // bf16 CB (swizzled): [20971528, 22020104)
#define O_P2    22020112   // partial kh=2
#define O_P3    26214416   // partial kh=3, ends 30408720 < 33554433
// beste is NOT materialized: k_quant decodes it from the one-hot ENC row (race-free).

#define AS1 __attribute__((address_space(1)))
#define AS3 __attribute__((address_space(3)))

__device__ __forceinline__ void gld_lds16(const void* g, void* l) {
    // async global->LDS, 16B per lane; LDS dest = wave-uniform base + lane*16
    __builtin_amdgcn_global_load_lds((AS1 const void*)g, (AS3 void*)l, 16, 0, 0);
}

// pack two fp32 into (bf16(hi)<<16)|bf16(lo) by truncation — one v_perm_b32
__device__ inline uint32_t pk2(float hi, float lo) {
    return __builtin_amdgcn_perm(__float_as_uint(hi), __float_as_uint(lo), 0x07060302u);
}

// ---------------- codebook norms (fp32) ----------------
__global__ __launch_bounds__(64) void k_enorm(const float* __restrict__ cb, float* __restrict__ enorm) {
    const int e = blockIdx.x;
    const int lane = threadIdx.x;
    const float4* c4 = (const float4*)(cb + (size_t)e * DIM);
    float p = 0.f;
#pragma unroll
    for (int j = 0; j < 16; j++) {
        float4 v = c4[j * 64 + lane];
        p = fmaf(v.x, v.x, fmaf(v.y, v.y, fmaf(v.z, v.z, fmaf(v.w, v.w, p))));
    }
    for (int off = 32; off; off >>= 1) p += __shfl_down(p, off);
    if (lane == 0) enorm[e] = p;
}

// ---------------- bf16 pack with per-row XOR swizzle ----------------
// Within each 64-elem K-block, 16B-chunk c of row r is stored at chunk (c ^ (r&7)).
// Block-partitioned: blocks [0,2048) pack X (2048 chunks each), [2048,2176) pack CB.
__global__ __launch_bounds__(256) void k_pack(const float* __restrict__ X, const float* __restrict__ CB,
                                              ushort_t* __restrict__ xbf, ushort_t* __restrict__ cbbf) {
    const int b = blockIdx.x;
    const float* src;
    ushort_t* dst;
    int c0;
    if (b < 2048) { src = X;  dst = xbf;  c0 = b * 2048; }
    else          { src = CB; dst = cbbf; c0 = (b - 2048) * 2048; }
#pragma unroll
    for (int it = 0; it < 8; it++) {
        const int c = c0 + it * 256 + threadIdx.x;
        const int r = c >> 9, g = c & 511;
        const int gs = (g & ~7) | ((g & 7) ^ (r & 7));
        const float4* s4 = (const float4*)(src + ((size_t)c << 3));
        float4 v0 = s4[0], v1 = s4[1];
        *(uint4*)(dst + (size_t)r * DIM + gs * 8) =
            make_uint4(pk2(v0.y, v0.x), pk2(v0.w, v0.z), pk2(v1.y, v1.x), pk2(v1.w, v1.z));
    }
}

// ---------------- bf16 score GEMM: BM=256, BN=256, BK=64, split-K=4, double-buffered ----------------
// 512 threads = 8 waves (2r x 4c); wave out = 128 rows x 64 cols (8x4 frags of 16x16x32).
// grid = 32 bm * 2 bn * 4 kh = 256 blocks = 1/CU. kh,bn in low bits -> fixed per XCD, so each
// XCD keeps its 0.5 MB codebook slice L2-resident and streams each A row exactly once.
// LDS 128 KiB: 2-phase T3 pipeline (stage next tile into other buffer, one barrier per step).
__global__ __launch_bounds__(512, 1) void k_gemm(const ushort_t* __restrict__ xbf, const ushort_t* __restrict__ cbbf,
                                                 const float* __restrict__ enorm,
                                                 float* __restrict__ P0g, float* __restrict__ P1g,
                                                 float* __restrict__ P2g, float* __restrict__ P3g) {
    __shared__ __align__(16) ushort_t As[2][256 * 64];   // 2 x 32 KiB
    __shared__ __align__(16) ushort_t Bs[2][256 * 64];   // 2 x 32 KiB
    const int bid = blockIdx.x;
    const int kh = bid & 3;
    const int bn = (bid >> 2) & 1;
    const int bm = bid >> 3;
    const int tid = threadIdx.x;
    const int lane = tid & 63;
    const int w = tid >> 6;
    const int wr = w >> 2, wc = w & 3;
    const int m16 = lane & 15, q4 = lane >> 4;

    // staging: lane l covers (row = l>>3, 16B chunk = l&7) of an 8-row stripe; load j = stripe j*64
    const int srow = lane >> 3;
    const int scol = (lane & 7) * 8;
    const ushort_t* ax = xbf + (size_t)(bm * 256 + w * 8 + srow) * DIM + kh * 1024 + scol;
    const ushort_t* bx = cbbf + (size_t)(bn * 256 + w * 8 + srow) * DIM + kh * 1024 + scol;

    floatx4 acc[8][4];
#pragma unroll
    for (int i = 0; i < 8; i++)
#pragma unroll
        for (int j = 0; j < 4; j++) acc[i][j] = (floatx4){0.f, 0.f, 0.f, 0.f};

    const int kx = (m16 & 7) * 8;  // frag-read XOR key (ushort units)

#define STAGE(BUF, KT)                                                                  \
    {                                                                                   \
        ushort_t* asd = &As[BUF][w * 512];                                              \
        ushort_t* bsd = &Bs[BUF][w * 512];                                              \
        _Pragma("unroll")                                                               \
        for (int j = 0; j < 4; j++) gld_lds16(ax + (size_t)j * 64 * DIM + (KT), asd + j * 4096); \
        _Pragma("unroll")                                                               \
        for (int j = 0; j < 4; j++) gld_lds16(bx + (size_t)j * 64 * DIM + (KT), bsd + j * 4096); \
    }

    STAGE(0, 0)
    asm volatile("s_waitcnt vmcnt(0)" ::: "memory");
    __syncthreads();

    int cur = 0;
    for (int kt = 0; kt < 1024; kt += 64) {
        if (kt + 64 < 1024) STAGE(cur ^ 1, kt + 64)   // issue next tile while computing this one
#pragma unroll
        for (int kk = 0; kk < 2; kk++) {
            short8 a[8], b[4];
#pragma unroll
            for (int i = 0; i < 8; i++)
                a[i] = *(const short8*)(&As[cur][(wr * 128 + i * 16 + m16) * 64 + ((kk * 32 + q4 * 8) ^ kx)]);
#pragma unroll
            for (int j = 0; j < 4; j++)
                b[j] = *(const short8*)(&Bs[cur][(wc * 64 + j * 16 + m16) * 64 + ((kk * 32 + q4 * 8) ^ kx)]);
#pragma unroll
            for (int i = 0; i < 8; i++)
#pragma unroll
                for (int j = 0; j < 4; j++)
                    acc[i][j] = __builtin_amdgcn_mfma_f32_16x16x32_bf16(a[i], b[j], acc[i][j], 0, 0, 0);
        }
        asm volatile("s_waitcnt vmcnt(0)" ::: "memory");
        __syncthreads();
        cur ^= 1;
    }
#undef STAGE

    // epilogue: P[kh==0] includes ||e||^2 ; C/D layout: col=lane&15, row=(lane>>4)*4+rr
    float* P = (kh == 0) ? P0g : (kh == 1) ? P1g : (kh == 2) ? P2g : P3g;
#pragma unroll
    for (int j = 0; j < 4; j++) {
        const int col = bn * 256 + wc * 64 + j * 16 + m16;
        const float en = (kh == 0) ? enorm[col] : 0.f;
#pragma unroll
        for (int i = 0; i < 8; i++) {
            const int row0 = bm * 256 + wr * 128 + i * 16 + q4 * 4;
#pragma unroll
            for (int rr = 0; rr < 4; rr++)
                P[(size_t)(row0 + rr) * E_CODES + col] = fmaf(-2.0f, acc[i][j][rr], en);
        }
    }
}

// ---------------- choose: wave-per-row argmin + (rare) exact refine + one-hot + counts ----------------
__global__ __launch_bounds__(256) void k_choose(const float* __restrict__ X, const float* __restrict__ CB,
                                                const float* __restrict__ P0, const float* __restrict__ P1,
                                                const float* __restrict__ P2, const float* __restrict__ P3,
                                                int* __restrict__ counts, float* __restrict__ out) {
    const int tid = threadIdx.x;
    const int lane = tid & 63, w = tid >> 6;
    const int row = blockIdx.x * 4 + w;
    const size_t ro = (size_t)row * E_CODES;

    float s[8];
#pragma unroll
    for (int g = 0; g < 8; g++) {
        const int c = g * 64 + lane;
        s[g] = (P0[ro + c] + P1[ro + c]) + (P2[ro + c] + P3[ro + c]);
    }

    // wave argmin (approx scores), tie -> lower index
    float mv = s[0]; int mi = lane;
#pragma unroll
    for (int g = 1; g < 8; g++) { if (s[g] < mv) { mv = s[g]; mi = g * 64 + lane; } }
    for (int off = 32; off; off >>= 1) {
        float ov = __shfl_xor(mv, off); int oi = __shfl_xor(mi, off);
        if (ov < mv || (ov == mv && oi < mi)) { mv = ov; mi = oi; }
    }
    const float thr = mv + MARGIN;

    unsigned long long m0 = __ballot(s[0] <= thr), m1 = __ballot(s[1] <= thr);
    unsigned long long m2 = __ballot(s[2] <= thr), m3 = __ballot(s[3] <= thr);
    unsigned long long m4 = __ballot(s[4] <= thr), m5 = __ballot(s[5] <= thr);
    unsigned long long m6 = __ballot(s[6] <= thr), m7 = __ballot(s[7] <= thr);
    const int ncand = __popcll(m0) + __popcll(m1) + __popcll(m2) + __popcll(m3) +
                      __popcll(m4) + __popcll(m5) + __popcll(m6) + __popcll(m7);

    int beste = mi;  // unique candidate == approx argmin
    if (ncand > 1) {
        const float4* xr4 = (const float4*)(X + (size_t)row * DIM);
        float bestd = 3.0e38f; beste = 1 << 30;
#define REFINE_GROUP(MG, G)                                                                 \
        {                                                                                   \
            unsigned long long mask = (MG);                                                 \
            while (mask) {                                                                  \
                const int b = __builtin_ctzll(mask); mask &= mask - 1;                      \
                const int e = (G) * 64 + b;                                                 \
                const float4* cr4 = (const float4*)(CB + (size_t)e * DIM);                  \
                float p = 0.f;                                                              \
                _Pragma("unroll")                                                           \
                for (int i = 0; i < 16; i++) {                                              \
                    float4 c = cr4[i * 64 + lane];                                          \
                    float4 x = xr4[i * 64 + lane];                                          \
                    float dx = x.x - c.x, dy = x.y - c.y, dz = x.z - c.z, dw = x.w - c.w;   \
                    p = fmaf(dx, dx, fmaf(dy, dy, fmaf(dz, dz, fmaf(dw, dw, p))));          \
                }                                                                           \
                for (int off = 32; off; off >>= 1) p += __shfl_xor(p, off);                 \
                if (p < bestd || (p == bestd && e < beste)) { bestd = p; beste = e; }       \
            }                                                                               \
        }
        REFINE_GROUP(m0, 0) REFINE_GROUP(m1, 1) REFINE_GROUP(m2, 2) REFINE_GROUP(m3, 3)
        REFINE_GROUP(m4, 4) REFINE_GROUP(m5, 5) REFINE_GROUP(m6, 6) REFINE_GROUP(m7, 7)
#undef REFINE_GROUP
    }

    // one-hot row (O_ENC is 8B-aligned -> float2). k_quant decodes beste from this row.
    float2* oe2 = (float2*)(out + O_ENC + (size_t)row * E_CODES);
#pragma unroll
    for (int k = 0; k < 4; k++) {
        const int e0 = (k * 64 + lane) * 2;
        float2 v; v.x = (e0 == beste) ? 1.0f : 0.0f; v.y = (e0 + 1 == beste) ? 1.0f : 0.0f;
        oe2[k * 64 + lane] = v;
    }

    if (lane == 0) atomicAdd(&counts[beste], 1);
}

// ---------------- quant: uniform streaming, 2 independent rows per wave ----------------
// Reads one-hot ENC rows (written by k_choose, never overwritten here) to recover beste.
// Loss: identical fma nest + 64-lane butterfly + one atomicAdd per row (bit pattern unchanged).
__global__ __launch_bounds__(256) void k_quant(const float* __restrict__ X, const float* __restrict__ CB,
                                               float* __restrict__ loss_sum, float* out) {
    const int tid = threadIdx.x;
    const int lane = tid & 63, w = tid >> 6;
    const int rA = blockIdx.x * 8 + w * 2;
    const int rB = rA + 1;

    // decode beste from one-hot rows
    const float2* eA2 = (const float2*)(out + O_ENC + (size_t)rA * E_CODES);
    const float2* eB2 = (const float2*)(out + O_ENC + (size_t)rB * E_CODES);
    int eA = 0, eB = 0;
#pragma unroll
    for (int k = 0; k < 4; k++) {
        float2 va = eA2[k * 64 + lane], vb = eB2[k * 64 + lane];
        unsigned long long ax = __ballot(va.x != 0.0f), ay = __ballot(va.y != 0.0f);
        unsigned long long bx = __ballot(vb.x != 0.0f), by = __ballot(vb.y != 0.0f);
        if (ax) eA = (k * 64 + __builtin_ctzll(ax)) * 2;
        if (ay) eA = (k * 64 + __builtin_ctzll(ay)) * 2 + 1;
        if (bx) eB = (k * 64 + __builtin_ctzll(bx)) * 2;
        if (by) eB = (k * 64 + __builtin_ctzll(by)) * 2 + 1;
    }

    const float4* xA = (const float4*)(X + (size_t)rA * DIM);
    const float4* xB = (const float4*)(X + (size_t)rB * DIM);
    const float4* qA = (const float4*)(CB + (size_t)eA * DIM);
    const float4* qB = (const float4*)(CB + (size_t)eB * DIM);
    f4u* oA = (f4u*)(out + O_Q + (size_t)rA * DIM);   // out+1 is only 4B-aligned
    f4u* oB = (f4u*)(out + O_Q + (size_t)rB * DIM);

    float pA = 0.f, pB = 0.f;
#pragma unroll
    for (int i = 0; i < 16; i++) {
        float4 xa = xA[i * 64 + lane], qa = qA[i * 64 + lane];
        float4 xb = xB[i * 64 + lane], qb = qB[i * 64 + lane];
        float dax = qa.x - xa.x, day = qa.y - xa.y, daz = qa.z - xa.z, daw = qa.w - xa.w;
        float dbx = qb.x - xb.x, dby = qb.y - xb.y, dbz = qb.z - xb.z, dbw = qb.w - xb.w;
        pA = fmaf(dax, dax, fmaf(day, day, fmaf(daz, daz, fmaf(daw, daw, pA))));
        pB = fmaf(dbx, dbx, fmaf(dby, dby, fmaf(dbz, dbz, fmaf(dbw, dbw, pB))));
        f4u ra, rb;
        ra.x = xa.x + dax; ra.y = xa.y + day; ra.z = xa.z + daz; ra.w = xa.w + daw;
        rb.x = xb.x + dbx; rb.y = xb.y + dby; rb.z = xb.z + dbz; rb.w = xb.w + dbw;
        oA[i * 64 + lane] = ra;
        oB[i * 64 + lane] = rb;
    }
    for (int off = 32; off; off >>= 1) { pA += __shfl_xor(pA, off); pB += __shfl_xor(pB, off); }

    if (lane == 0) {
        atomicAdd(loss_sum, pA);
        atomicAdd(loss_sum, pB);
    }
}

// ---------------- loss + perplexity ----------------
__global__ __launch_bounds__(512) void k_final(const int* __restrict__ counts, const float* __restrict__ loss_sum,
                                               float* __restrict__ out) {
    const int tid = threadIdx.x;
    const int lane = tid & 63, w = tid >> 6;
    __shared__ float r[8];
    const float p = (float)counts[tid] * (1.0f / 8192.0f);
    float h = p * logf(p + 1e-10f);
    for (int off = 32; off; off >>= 1) h += __shfl_down(h, off);
    if (lane == 0) r[w] = h;
    __syncthreads();
    if (tid == 0) {
        float H = 0.f;
        for (int k = 0; k < 8; k++) H += r[k];
        out[O_PERP] = expf(-H);
        out[O_LOSS] = loss_sum[0] * (1.25f / 33554432.0f);  // q_latent + 0.25*e_latent = 1.25*MSE
    }
}

extern "C" void kernel_launch(void* const* d_in, const int* in_sizes, int n_in,
                              void* d_out, int out_size, void* d_ws, size_t ws_size,
                              hipStream_t stream) {
    const float* X  = (const float*)d_in[0];   // inputs  [8192, 8,8,8,8] -> [8192,4096]
    const float* CB = (const float*)d_in[1];   // codebook [512, 4096]
    float* out = (float*)d_out;
    float* ws  = (float*)d_ws;
    float* p0     = ws + WS_P0;
    float* enorm  = ws + WS_ENORM;
    int*   counts = (int*)(ws + WS_COUNTS);
    float* loss_s = ws + WS_LOSS;
    ushort_t* xbf  = (ushort_t*)(out + O_XBF);
    ushort_t* cbbf = (ushort_t*)(out + O_CBBF);
    float* p1 = out + O_P1;
    float* p2 = out + O_P2;
    float* p3 = out + O_P3;

    hipMemsetAsync(counts, 0, (E_CODES + 1) * sizeof(int), stream);

    k_pack<<<2176, 256, 0, stream>>>(X, CB, xbf, cbbf);
    k_enorm<<<E_CODES, 64, 0, stream>>>(CB, enorm);
    k_gemm<<<256, 512, 0, stream>>>(xbf, cbbf, enorm, p0, p1, p2, p3);
    k_choose<<<B_ROWS / 4, 256, 0, stream>>>(X, CB, p0, p1, p2, p3, counts, out);
    k_quant<<<B_ROWS / 8, 256, 0, stream>>>(X, CB, loss_s, out);
    k_final<<<1, 512, 0, stream>>>(counts, loss_s, out);
}

// Round 5
// 460.150 us; speedup vs baseline: 1.1225x; 1.1225x over previous
//
#include <hip/hip_runtime.h>
#include <stdint.h>

#define B_ROWS 8192
#define DIM 4096
#define E_CODES 512
#define MARGIN 16.0f

typedef __attribute__((ext_vector_type(8))) short short8;
typedef __attribute__((ext_vector_type(4))) float floatx4;
typedef __attribute__((ext_vector_type(4), aligned(4))) float f4u;  // unaligned-ok float4
typedef unsigned short ushort_t;

// ---- workspace layout (float units) ----
#define WS_SCORES 0                       // final scores: 8192*512 floats
#define WS_ENORM  4194304                 // 512 floats
#define WS_COUNTS 4194816                 // 512 ints
#define WS_LOSS   4195328                 // 1 float

// ---- output layout (float units) ----
#define O_LOSS 0
#define O_Q    1
#define O_PERP 33554433
#define O_ENC  33554434
// scratch carved out of the Q region (fully overwritten by k_fused afterwards):
#define O_XBF   4          // bf16 X (swizzled): [4, 16777220)
#define O_CBBF  20971528   // bf16 CB (swizzled): [20971528, 22020104)

#define AS1 __attribute__((address_space(1)))
#define AS3 __attribute__((address_space(3)))

__device__ __forceinline__ void gld_lds16(const void* g, void* l) {
    // async global->LDS, 16B per lane; LDS dest = wave-uniform base + lane*16
    __builtin_amdgcn_global_load_lds((AS1 const void*)g, (AS3 void*)l, 16, 0, 0);
}

// pack two fp32 into (bf16(hi)<<16)|bf16(lo) by truncation — one v_perm_b32
__device__ inline uint32_t pk2(float hi, float lo) {
    return __builtin_amdgcn_perm(__float_as_uint(hi), __float_as_uint(lo), 0x07060302u);
}

// ---------------- codebook norms (fp32) ----------------
__global__ __launch_bounds__(64) void k_enorm(const float* __restrict__ cb, float* __restrict__ enorm) {
    const int e = blockIdx.x;
    const int lane = threadIdx.x;
    const float4* c4 = (const float4*)(cb + (size_t)e * DIM);
    float p = 0.f;
#pragma unroll
    for (int j = 0; j < 16; j++) {
        float4 v = c4[j * 64 + lane];
        p = fmaf(v.x, v.x, fmaf(v.y, v.y, fmaf(v.z, v.z, fmaf(v.w, v.w, p))));
    }
    for (int off = 32; off; off >>= 1) p += __shfl_down(p, off);
    if (lane == 0) enorm[e] = p;
}

// ---------------- bf16 pack with per-row XOR swizzle ----------------
// Within each 64-elem K-block, 16B-chunk c of row r is stored at chunk (c ^ (r&7)).
// Block-partitioned: blocks [0,2048) pack X (2048 chunks each), [2048,2176) pack CB.
__global__ __launch_bounds__(256) void k_pack(const float* __restrict__ X, const float* __restrict__ CB,
                                              ushort_t* __restrict__ xbf, ushort_t* __restrict__ cbbf) {
    const int b = blockIdx.x;
    const float* src;
    ushort_t* dst;
    int c0;
    if (b < 2048) { src = X;  dst = xbf;  c0 = b * 2048; }
    else          { src = CB; dst = cbbf; c0 = (b - 2048) * 2048; }
#pragma unroll
    for (int it = 0; it < 8; it++) {
        const int c = c0 + it * 256 + threadIdx.x;
        const int r = c >> 9, g = c & 511;
        const int gs = (g & ~7) | ((g & 7) ^ (r & 7));
        const float4* s4 = (const float4*)(src + ((size_t)c << 3));
        float4 v0 = s4[0], v1 = s4[1];
        *(uint4*)(dst + (size_t)r * DIM + gs * 8) =
            make_uint4(pk2(v0.y, v0.x), pk2(v0.w, v0.z), pk2(v1.y, v1.x), pk2(v1.w, v1.z));
    }
}

// ---------------- bf16 score GEMM: BM=64, BN=128, BK=64, NO split-K, double-buffered ----------------
// 256 threads = 4 waves (2r x 2c); wave out = 32 rows x 64 cols (2x4 frags of 16x16x32).
// grid = 128 bm * 4 bn = 512 blocks = 2/CU (48 KiB LDS), 8 waves/CU.
// bn = bid&3 is fixed per XCD (bid&7 = XCD) -> each XCD streams a 1 MB cbbf slice, L2-resident.
// xbf is read exactly once. Epilogue writes final scores (16.8 MB), including ||e||^2.
__global__ __launch_bounds__(256, 2) void k_gemm(const ushort_t* __restrict__ xbf, const ushort_t* __restrict__ cbbf,
                                                 const float* __restrict__ enorm, float* __restrict__ scores) {
    __shared__ __align__(16) ushort_t As[2][64 * 64];    // 2 x 8 KiB
    __shared__ __align__(16) ushort_t Bs[2][128 * 64];   // 2 x 16 KiB
    const int bid = blockIdx.x;
    const int bn = bid & 3;
    const int bm = bid >> 2;
    const int tid = threadIdx.x;
    const int lane = tid & 63;
    const int w = tid >> 6;
    const int wr = w >> 1, wc = w & 1;
    const int m16 = lane & 15, q4 = lane >> 4;

    // staging: lane l covers (row = l>>3, 16B chunk = l&7) of an 8-row stripe; stripe j = j*32 + w*8
    const int srow = lane >> 3;
    const int scol = (lane & 7) * 8;
    const ushort_t* ax = xbf + (size_t)(bm * 64 + w * 8 + srow) * DIM + scol;
    const ushort_t* bx = cbbf + (size_t)(bn * 128 + w * 8 + srow) * DIM + scol;

    floatx4 acc[2][4];
#pragma unroll
    for (int i = 0; i < 2; i++)
#pragma unroll
        for (int j = 0; j < 4; j++) acc[i][j] = (floatx4){0.f, 0.f, 0.f, 0.f};

    const int kx = (m16 & 7) * 8;  // frag-read XOR key (ushort units)

#define STAGE(BUF, KT)                                                                      \
    {                                                                                       \
        _Pragma("unroll")                                                                   \
        for (int j = 0; j < 2; j++)                                                         \
            gld_lds16(ax + (size_t)j * 32 * DIM + (KT), &As[BUF][(j * 32 + w * 8) * 64]);   \
        _Pragma("unroll")                                                                   \
        for (int j = 0; j < 4; j++)                                                         \
            gld_lds16(bx + (size_t)j * 32 * DIM + (KT), &Bs[BUF][(j * 32 + w * 8) * 64]);   \
    }

    STAGE(0, 0)
    asm volatile("s_waitcnt vmcnt(0)" ::: "memory");
    __syncthreads();

    int cur = 0;
    for (int kt = 0; kt < DIM; kt += 64) {
        if (kt + 64 < DIM) STAGE(cur ^ 1, kt + 64)   // issue next tile while computing this one
#pragma unroll
        for (int kk = 0; kk < 2; kk++) {
            short8 a[2], b[4];
#pragma unroll
            for (int i = 0; i < 2; i++)
                a[i] = *(const short8*)(&As[cur][(wr * 32 + i * 16 + m16) * 64 + ((kk * 32 + q4 * 8) ^ kx)]);
#pragma unroll
            for (int j = 0; j < 4; j++)
                b[j] = *(const short8*)(&Bs[cur][(wc * 64 + j * 16 + m16) * 64 + ((kk * 32 + q4 * 8) ^ kx)]);
#pragma unroll
            for (int i = 0; i < 2; i++)
#pragma unroll
                for (int j = 0; j < 4; j++)
                    acc[i][j] = __builtin_amdgcn_mfma_f32_16x16x32_bf16(a[i], b[j], acc[i][j], 0, 0, 0);
        }
        asm volatile("s_waitcnt vmcnt(0)" ::: "memory");
        __syncthreads();
        cur ^= 1;
    }
#undef STAGE

    // epilogue: score = ||e||^2 - 2*dot ; C/D layout: col=lane&15, row=(lane>>4)*4+rr
#pragma unroll
    for (int j = 0; j < 4; j++) {
        const int col = bn * 128 + wc * 64 + j * 16 + m16;
        const float en = enorm[col];
#pragma unroll
        for (int i = 0; i < 2; i++) {
            const int row0 = bm * 64 + wr * 32 + i * 16 + q4 * 4;
#pragma unroll
            for (int rr = 0; rr < 4; rr++)
                scores[(size_t)(row0 + rr) * E_CODES + col] = fmaf(-2.0f, acc[i][j][rr], en);
        }
    }
}

// ---------------- fused: wave-per-row argmin + (rare) exact refine + quantize + one-hot + loss ------
// Q-write pass explicitly pipelined: all 32 float4 loads issued as named registers before the
// fma/store chain (forces MLP; loss fma-nest order i=0..15 unchanged -> bitwise-identical loss).
__global__ __launch_bounds__(256) void k_fused(const float* __restrict__ X, const float* __restrict__ CB,
                                               const float* __restrict__ scores,
                                               int* __restrict__ counts, float* __restrict__ loss_sum,
                                               float* __restrict__ out) {
    const int tid = threadIdx.x;
    const int lane = tid & 63, w = tid >> 6;
    const int row = blockIdx.x * 4 + w;

    const float* sr = scores + (size_t)row * E_CODES;
    float s[8];
#pragma unroll
    for (int g = 0; g < 8; g++) s[g] = sr[g * 64 + lane];

    // wave argmin (approx scores), tie -> lower index
    float mv = s[0]; int mi = lane;
#pragma unroll
    for (int g = 1; g < 8; g++) { if (s[g] < mv) { mv = s[g]; mi = g * 64 + lane; } }
    for (int off = 32; off; off >>= 1) {
        float ov = __shfl_xor(mv, off); int oi = __shfl_xor(mi, off);
        if (ov < mv || (ov == mv && oi < mi)) { mv = ov; mi = oi; }
    }
    const float thr = mv + MARGIN;

    unsigned long long m0 = __ballot(s[0] <= thr), m1 = __ballot(s[1] <= thr);
    unsigned long long m2 = __ballot(s[2] <= thr), m3 = __ballot(s[3] <= thr);
    unsigned long long m4 = __ballot(s[4] <= thr), m5 = __ballot(s[5] <= thr);
    unsigned long long m6 = __ballot(s[6] <= thr), m7 = __ballot(s[7] <= thr);
    const int ncand = __popcll(m0) + __popcll(m1) + __popcll(m2) + __popcll(m3) +
                      __popcll(m4) + __popcll(m5) + __popcll(m6) + __popcll(m7);

    const float4* xr4 = (const float4*)(X + (size_t)row * DIM);
    int beste = mi;  // unique candidate == approx argmin

    if (ncand > 1) {
        // exact fp32 refine over margin candidates; butterfly sums bit-identical on all lanes
        float bestd = 3.0e38f; beste = 1 << 30;
#define REFINE_GROUP(MG, G)                                                                 \
        {                                                                                   \
            unsigned long long mask = (MG);                                                 \
            while (mask) {                                                                  \
                const int b = __builtin_ctzll(mask); mask &= mask - 1;                      \
                const int e = (G) * 64 + b;                                                 \
                const float4* cr4 = (const float4*)(CB + (size_t)e * DIM);                  \
                float p = 0.f;                                                              \
                _Pragma("unroll")                                                           \
                for (int i = 0; i < 16; i++) {                                              \
                    float4 c = cr4[i * 64 + lane];                                          \
                    float4 x = xr4[i * 64 + lane];                                          \
                    float dx = x.x - c.x, dy = x.y - c.y, dz = x.z - c.z, dw = x.w - c.w;   \
                    p = fmaf(dx, dx, fmaf(dy, dy, fmaf(dz, dz, fmaf(dw, dw, p))));          \
                }                                                                           \
                for (int off = 32; off; off >>= 1) p += __shfl_xor(p, off);                 \
                if (p < bestd || (p == bestd && e < beste)) { bestd = p; beste = e; }       \
            }                                                                               \
        }
        REFINE_GROUP(m0, 0) REFINE_GROUP(m1, 1) REFINE_GROUP(m2, 2) REFINE_GROUP(m3, 3)
        REFINE_GROUP(m4, 4) REFINE_GROUP(m5, 5) REFINE_GROUP(m6, 6) REFINE_GROUP(m7, 7)
#undef REFINE_GROUP
    }

    // quantized_st = x + (q - x); loss fma-nest i=0..15 + butterfly (bitwise same as baseline).
    const float4* cq4 = (const float4*)(CB + (size_t)beste * DIM);
    f4u* oq4 = (f4u*)(out + O_Q + (size_t)row * DIM);   // out+1 is only 4B-aligned

    // issue ALL loads first (named registers -> ~128 VGPR of outstanding loads)
#define LD(K) float4 x##K = xr4[(K) * 64 + lane]; float4 q##K = cq4[(K) * 64 + lane];
    LD(0) LD(1) LD(2) LD(3) LD(4) LD(5) LD(6) LD(7)
    LD(8) LD(9) LD(10) LD(11) LD(12) LD(13) LD(14) LD(15)
#undef LD
    float p = 0.f;
#define ST(K)                                                                               \
    {                                                                                       \
        float dx = q##K.x - x##K.x, dy = q##K.y - x##K.y;                                   \
        float dz = q##K.z - x##K.z, dw = q##K.w - x##K.w;                                   \
        p = fmaf(dx, dx, fmaf(dy, dy, fmaf(dz, dz, fmaf(dw, dw, p))));                      \
        f4u r;                                                                              \
        r.x = x##K.x + dx; r.y = x##K.y + dy; r.z = x##K.z + dz; r.w = x##K.w + dw;         \
        oq4[(K) * 64 + lane] = r;                                                           \
    }
    ST(0) ST(1) ST(2) ST(3) ST(4) ST(5) ST(6) ST(7)
    ST(8) ST(9) ST(10) ST(11) ST(12) ST(13) ST(14) ST(15)
#undef ST
    for (int off = 32; off; off >>= 1) p += __shfl_xor(p, off);

    // one-hot row (O_ENC is 8B-aligned -> float2)
    float2* oe2 = (float2*)(out + O_ENC + (size_t)row * E_CODES);
#pragma unroll
    for (int k = 0; k < 4; k++) {
        const int e0 = (k * 64 + lane) * 2;
        float2 v; v.x = (e0 == beste) ? 1.0f : 0.0f; v.y = (e0 + 1 == beste) ? 1.0f : 0.0f;
        oe2[k * 64 + lane] = v;
    }

    if (lane == 0) {
        atomicAdd(&counts[beste], 1);
        atomicAdd(loss_sum, p);          // p == sum((q-x)^2), exact fp32
    }
}

// ---------------- loss + perplexity ----------------
__global__ __launch_bounds__(512) void k_final(const int* __restrict__ counts, const float* __restrict__ loss_sum,
                                               float* __restrict__ out) {
    const int tid = threadIdx.x;
    const int lane = tid & 63, w = tid >> 6;
    __shared__ float r[8];
    const float p = (float)counts[tid] * (1.0f / 8192.0f);
    float h = p * logf(p + 1e-10f);
    for (int off = 32; off; off >>= 1) h += __shfl_down(h, off);
    if (lane == 0) r[w] = h;
    __syncthreads();
    if (tid == 0) {
        float H = 0.f;
        for (int k = 0; k < 8; k++) H += r[k];
        out[O_PERP] = expf(-H);
        out[O_LOSS] = loss_sum[0] * (1.25f / 33554432.0f);  // q_latent + 0.25*e_latent = 1.25*MSE
    }
}

extern "C" void kernel_launch(void* const* d_in, const int* in_sizes, int n_in,
                              void* d_out, int out_size, void* d_ws, size_t ws_size,
                              hipStream_t stream) {
    const float* X  = (const float*)d_in[0];   // inputs  [8192, 8,8,8,8] -> [8192,4096]
    const float* CB = (const float*)d_in[1];   // codebook [512, 4096]
    float* out = (float*)d_out;
    float* ws  = (float*)d_ws;
    float* scores = ws + WS_SCORES;
    float* enorm  = ws + WS_ENORM;
    int*   counts = (int*)(ws + WS_COUNTS);
    float* loss_s = ws + WS_LOSS;
    ushort_t* xbf  = (ushort_t*)(out + O_XBF);
    ushort_t* cbbf = (ushort_t*)(out + O_CBBF);

    hipMemsetAsync(counts, 0, (E_CODES + 1) * sizeof(int), stream);

    k_pack<<<2176, 256, 0, stream>>>(X, CB, xbf, cbbf);
    k_enorm<<<E_CODES, 64, 0, stream>>>(CB, enorm);
    k_gemm<<<512, 256, 0, stream>>>(xbf, cbbf, enorm, scores);
    k_fused<<<B_ROWS / 4, 256, 0, stream>>>(X, CB, scores, counts, loss_s, out);
    k_final<<<1, 512, 0, stream>>>(counts, loss_s, out);
}

// Round 6
// 413.092 us; speedup vs baseline: 1.2504x; 1.1139x over previous
//
#include <hip/hip_runtime.h>
#include <stdint.h>

#define B_ROWS 8192
#define DIM 4096
#define E_CODES 512
#define MARGIN 16.0f

typedef __attribute__((ext_vector_type(8))) short short8;
typedef __attribute__((ext_vector_type(4))) float floatx4;
typedef __attribute__((ext_vector_type(4), aligned(4))) float f4u;  // unaligned-ok float4
typedef unsigned short ushort_t;

// ---- workspace layout (float units) ----
#define WS_SCORES 0                       // final scores: 8192*512 floats
#define WS_ENORM  4194304                 // 512 floats: ||e||^2 for k_gemm, then ZEROED and
                                          // reused as 512 loss partial-sum slots for k_fused
#define WS_COUNTS 4194816                 // 512 ints
#define WS_LOSS   4195328                 // (unused this round)

// ---- output layout (float units) ----
#define O_LOSS 0
#define O_Q    1
#define O_PERP 33554433
#define O_ENC  33554434
// scratch carved out of the Q region (fully overwritten by k_fused afterwards):
#define O_XBF   4          // bf16 X (swizzled): [4, 16777220)
#define O_CBBF  20971528   // bf16 CB (swizzled): [20971528, 22020104)

#define AS1 __attribute__((address_space(1)))
#define AS3 __attribute__((address_space(3)))

__device__ __forceinline__ void gld_lds16(const void* g, void* l) {
    // async global->LDS, 16B per lane; LDS dest = wave-uniform base + lane*16
    __builtin_amdgcn_global_load_lds((AS1 const void*)g, (AS3 void*)l, 16, 0, 0);
}

// pack two fp32 into (bf16(hi)<<16)|bf16(lo) by truncation — one v_perm_b32
__device__ inline uint32_t pk2(float hi, float lo) {
    return __builtin_amdgcn_perm(__float_as_uint(hi), __float_as_uint(lo), 0x07060302u);
}

// ---------------- codebook norms (fp32) ----------------
__global__ __launch_bounds__(64) void k_enorm(const float* __restrict__ cb, float* __restrict__ enorm) {
    const int e = blockIdx.x;
    const int lane = threadIdx.x;
    const float4* c4 = (const float4*)(cb + (size_t)e * DIM);
    float p = 0.f;
#pragma unroll
    for (int j = 0; j < 16; j++) {
        float4 v = c4[j * 64 + lane];
        p = fmaf(v.x, v.x, fmaf(v.y, v.y, fmaf(v.z, v.z, fmaf(v.w, v.w, p))));
    }
    for (int off = 32; off; off >>= 1) p += __shfl_down(p, off);
    if (lane == 0) enorm[e] = p;
}

// ---------------- bf16 pack with per-row XOR swizzle ----------------
// Within each 64-elem K-block, 16B-chunk c of row r is stored at chunk (c ^ (r&7)).
// Block-partitioned: blocks [0,2048) pack X (2048 chunks each), [2048,2176) pack CB.
__global__ __launch_bounds__(256) void k_pack(const float* __restrict__ X, const float* __restrict__ CB,
                                              ushort_t* __restrict__ xbf, ushort_t* __restrict__ cbbf) {
    const int b = blockIdx.x;
    const float* src;
    ushort_t* dst;
    int c0;
    if (b < 2048) { src = X;  dst = xbf;  c0 = b * 2048; }
    else          { src = CB; dst = cbbf; c0 = (b - 2048) * 2048; }
#pragma unroll
    for (int it = 0; it < 8; it++) {
        const int c = c0 + it * 256 + threadIdx.x;
        const int r = c >> 9, g = c & 511;
        const int gs = (g & ~7) | ((g & 7) ^ (r & 7));
        const float4* s4 = (const float4*)(src + ((size_t)c << 3));
        float4 v0 = s4[0], v1 = s4[1];
        *(uint4*)(dst + (size_t)r * DIM + gs * 8) =
            make_uint4(pk2(v0.y, v0.x), pk2(v0.w, v0.z), pk2(v1.y, v1.x), pk2(v1.w, v1.z));
    }
}

// ---------------- bf16 score GEMM: BM=64, BN=128, BK=64, NO split-K, double-buffered ----------------
// 256 threads = 4 waves (2r x 2c); wave out = 32 rows x 64 cols (2x4 frags of 16x16x32).
// grid = 128 bm * 4 bn = 512 blocks = 2/CU (48 KiB LDS), 8 waves/CU.
// bn = bid&3 is fixed per XCD -> each XCD streams a 1 MB cbbf slice, L2-resident.
__global__ __launch_bounds__(256, 2) void k_gemm(const ushort_t* __restrict__ xbf, const ushort_t* __restrict__ cbbf,
                                                 const float* __restrict__ enorm, float* __restrict__ scores) {
    __shared__ __align__(16) ushort_t As[2][64 * 64];    // 2 x 8 KiB
    __shared__ __align__(16) ushort_t Bs[2][128 * 64];   // 2 x 16 KiB
    const int bid = blockIdx.x;
    const int bn = bid & 3;
    const int bm = bid >> 2;
    const int tid = threadIdx.x;
    const int lane = tid & 63;
    const int w = tid >> 6;
    const int wr = w >> 1, wc = w & 1;
    const int m16 = lane & 15, q4 = lane >> 4;

    const int srow = lane >> 3;
    const int scol = (lane & 7) * 8;
    const ushort_t* ax = xbf + (size_t)(bm * 64 + w * 8 + srow) * DIM + scol;
    const ushort_t* bx = cbbf + (size_t)(bn * 128 + w * 8 + srow) * DIM + scol;

    floatx4 acc[2][4];
#pragma unroll
    for (int i = 0; i < 2; i++)
#pragma unroll
        for (int j = 0; j < 4; j++) acc[i][j] = (floatx4){0.f, 0.f, 0.f, 0.f};

    const int kx = (m16 & 7) * 8;  // frag-read XOR key (ushort units)

#define STAGE(BUF, KT)                                                                      \
    {                                                                                       \
        _Pragma("unroll")                                                                   \
        for (int j = 0; j < 2; j++)                                                         \
            gld_lds16(ax + (size_t)j * 32 * DIM + (KT), &As[BUF][(j * 32 + w * 8) * 64]);   \
        _Pragma("unroll")                                                                   \
        for (int j = 0; j < 4; j++)                                                         \
            gld_lds16(bx + (size_t)j * 32 * DIM + (KT), &Bs[BUF][(j * 32 + w * 8) * 64]);   \
    }

    STAGE(0, 0)
    asm volatile("s_waitcnt vmcnt(0)" ::: "memory");
    __syncthreads();

    int cur = 0;
    for (int kt = 0; kt < DIM; kt += 64) {
        if (kt + 64 < DIM) STAGE(cur ^ 1, kt + 64)   // issue next tile while computing this one
#pragma unroll
        for (int kk = 0; kk < 2; kk++) {
            short8 a[2], b[4];
#pragma unroll
            for (int i = 0; i < 2; i++)
                a[i] = *(const short8*)(&As[cur][(wr * 32 + i * 16 + m16) * 64 + ((kk * 32 + q4 * 8) ^ kx)]);
#pragma unroll
            for (int j = 0; j < 4; j++)
                b[j] = *(const short8*)(&Bs[cur][(wc * 64 + j * 16 + m16) * 64 + ((kk * 32 + q4 * 8) ^ kx)]);
#pragma unroll
            for (int i = 0; i < 2; i++)
#pragma unroll
                for (int j = 0; j < 4; j++)
                    acc[i][j] = __builtin_amdgcn_mfma_f32_16x16x32_bf16(a[i], b[j], acc[i][j], 0, 0, 0);
        }
        asm volatile("s_waitcnt vmcnt(0)" ::: "memory");
        __syncthreads();
        cur ^= 1;
    }
#undef STAGE

    // epilogue: score = ||e||^2 - 2*dot ; C/D layout: col=lane&15, row=(lane>>4)*4+rr
#pragma unroll
    for (int j = 0; j < 4; j++) {
        const int col = bn * 128 + wc * 64 + j * 16 + m16;
        const float en = enorm[col];
#pragma unroll
        for (int i = 0; i < 2; i++) {
            const int row0 = bm * 64 + wr * 32 + i * 16 + q4 * 4;
#pragma unroll
            for (int rr = 0; rr < 4; rr++)
                scores[(size_t)(row0 + rr) * E_CODES + col] = fmaf(-2.0f, acc[i][j][rr], en);
        }
    }
}

// ---------------- fused: argmin + (rare) exact refine + quantize + one-hot + loss ----------------
// Loss accumulation: per-wave butterfly (bitwise as before) -> per-block LDS reduce ->
// ONE atomicAdd per block into lossp[blockIdx&511] (~4 adds/slot). No same-address chain.
__global__ __launch_bounds__(256) void k_fused(const float* __restrict__ X, const float* __restrict__ CB,
                                               const float* __restrict__ scores,
                                               int* __restrict__ counts, float* __restrict__ lossp,
                                               float* __restrict__ out) {
    __shared__ float lred[4];
    const int tid = threadIdx.x;
    const int lane = tid & 63, w = tid >> 6;
    const int row = blockIdx.x * 4 + w;

    const float* sr = scores + (size_t)row * E_CODES;
    float s[8];
#pragma unroll
    for (int g = 0; g < 8; g++) s[g] = sr[g * 64 + lane];

    // wave argmin (approx scores), tie -> lower index
    float mv = s[0]; int mi = lane;
#pragma unroll
    for (int g = 1; g < 8; g++) { if (s[g] < mv) { mv = s[g]; mi = g * 64 + lane; } }
    for (int off = 32; off; off >>= 1) {
        float ov = __shfl_xor(mv, off); int oi = __shfl_xor(mi, off);
        if (ov < mv || (ov == mv && oi < mi)) { mv = ov; mi = oi; }
    }
    const float thr = mv + MARGIN;

    unsigned long long m0 = __ballot(s[0] <= thr), m1 = __ballot(s[1] <= thr);
    unsigned long long m2 = __ballot(s[2] <= thr), m3 = __ballot(s[3] <= thr);
    unsigned long long m4 = __ballot(s[4] <= thr), m5 = __ballot(s[5] <= thr);
    unsigned long long m6 = __ballot(s[6] <= thr), m7 = __ballot(s[7] <= thr);
    const int ncand = __popcll(m0) + __popcll(m1) + __popcll(m2) + __popcll(m3) +
                      __popcll(m4) + __popcll(m5) + __popcll(m6) + __popcll(m7);

    const float4* xr4 = (const float4*)(X + (size_t)row * DIM);
    int beste = mi;  // unique candidate == approx argmin

    if (ncand > 1) {
        // exact fp32 refine over margin candidates; butterfly sums bit-identical on all lanes
        float bestd = 3.0e38f; beste = 1 << 30;
#define REFINE_GROUP(MG, G)                                                                 \
        {                                                                                   \
            unsigned long long mask = (MG);                                                 \
            while (mask) {                                                                  \
                const int b = __builtin_ctzll(mask); mask &= mask - 1;                      \
                const int e = (G) * 64 + b;                                                 \
                const float4* cr4 = (const float4*)(CB + (size_t)e * DIM);                  \
                float p = 0.f;                                                              \
                _Pragma("unroll")                                                           \
                for (int i = 0; i < 16; i++) {                                              \
                    float4 c = cr4[i * 64 + lane];                                          \
                    float4 x = xr4[i * 64 + lane];                                          \
                    float dx = x.x - c.x, dy = x.y - c.y, dz = x.z - c.z, dw = x.w - c.w;   \
                    p = fmaf(dx, dx, fmaf(dy, dy, fmaf(dz, dz, fmaf(dw, dw, p))));          \
                }                                                                           \
                for (int off = 32; off; off >>= 1) p += __shfl_xor(p, off);                 \
                if (p < bestd || (p == bestd && e < beste)) { bestd = p; beste = e; }       \
            }                                                                               \
        }
        REFINE_GROUP(m0, 0) REFINE_GROUP(m1, 1) REFINE_GROUP(m2, 2) REFINE_GROUP(m3, 3)
        REFINE_GROUP(m4, 4) REFINE_GROUP(m5, 5) REFINE_GROUP(m6, 6) REFINE_GROUP(m7, 7)
#undef REFINE_GROUP
    }

    // quantized_st = x + (q - x); loss fma-nest i=0..15 + butterfly (bitwise same as baseline).
    const float4* cq4 = (const float4*)(CB + (size_t)beste * DIM);
    f4u* oq4 = (f4u*)(out + O_Q + (size_t)row * DIM);   // out+1 is only 4B-aligned

#define LD(K) float4 x##K = xr4[(K) * 64 + lane]; float4 q##K = cq4[(K) * 64 + lane];
    LD(0) LD(1) LD(2) LD(3) LD(4) LD(5) LD(6) LD(7)
    LD(8) LD(9) LD(10) LD(11) LD(12) LD(13) LD(14) LD(15)
#undef LD
    float p = 0.f;
#define ST(K)                                                                               \
    {                                                                                       \
        float dx = q##K.x - x##K.x, dy = q##K.y - x##K.y;                                   \
        float dz = q##K.z - x##K.z, dw = q##K.w - x##K.w;                                   \
        p = fmaf(dx, dx, fmaf(dy, dy, fmaf(dz, dz, fmaf(dw, dw, p))));                      \
        f4u r;                                                                              \
        r.x = x##K.x + dx; r.y = x##K.y + dy; r.z = x##K.z + dz; r.w = x##K.w + dw;         \
        oq4[(K) * 64 + lane] = r;                                                           \
    }
    ST(0) ST(1) ST(2) ST(3) ST(4) ST(5) ST(6) ST(7)
    ST(8) ST(9) ST(10) ST(11) ST(12) ST(13) ST(14) ST(15)
#undef ST
    for (int off = 32; off; off >>= 1) p += __shfl_xor(p, off);

    // one-hot row (O_ENC is 8B-aligned -> float2)
    float2* oe2 = (float2*)(out + O_ENC + (size_t)row * E_CODES);
#pragma unroll
    for (int k = 0; k < 4; k++) {
        const int e0 = (k * 64 + lane) * 2;
        float2 v; v.x = (e0 == beste) ? 1.0f : 0.0f; v.y = (e0 + 1 == beste) ? 1.0f : 0.0f;
        oe2[k * 64 + lane] = v;
    }

    // loss: block-level reduce, single spread-slot atomic per block (kills the 8192-deep
    // same-address atomic chain that serialized every previous streaming kernel).
    if (lane == 0) {
        lred[w] = p;
        atomicAdd(&counts[beste], 1);   // 512 spread addresses — cheap
    }
    __syncthreads();
    if (tid == 0) {
        float P = ((lred[0] + lred[1]) + lred[2]) + lred[3];
        atomicAdd(&lossp[blockIdx.x & 511], P);
    }
}

// ---------------- loss + perplexity ----------------
__global__ __launch_bounds__(512) void k_final(const int* __restrict__ counts, const float* __restrict__ lossp,
                                               float* __restrict__ out) {
    const int tid = threadIdx.x;
    const int lane = tid & 63, w = tid >> 6;
    __shared__ float r[8];
    __shared__ float r2[8];
    const float p = (float)counts[tid] * (1.0f / 8192.0f);
    float h = p * logf(p + 1e-10f);
    float l = lossp[tid];
    for (int off = 32; off; off >>= 1) { h += __shfl_down(h, off); l += __shfl_down(l, off); }
    if (lane == 0) { r[w] = h; r2[w] = l; }
    __syncthreads();
    if (tid == 0) {
        float H = 0.f, L = 0.f;
        for (int k = 0; k < 8; k++) { H += r[k]; L += r2[k]; }
        out[O_PERP] = expf(-H);
        out[O_LOSS] = L * (1.25f / 33554432.0f);  // q_latent + 0.25*e_latent = 1.25*MSE
    }
}

extern "C" void kernel_launch(void* const* d_in, const int* in_sizes, int n_in,
                              void* d_out, int out_size, void* d_ws, size_t ws_size,
                              hipStream_t stream) {
    const float* X  = (const float*)d_in[0];   // inputs  [8192, 8,8,8,8] -> [8192,4096]
    const float* CB = (const float*)d_in[1];   // codebook [512, 4096]
    float* out = (float*)d_out;
    float* ws  = (float*)d_ws;
    float* scores = ws + WS_SCORES;
    float* enorm  = ws + WS_ENORM;   // doubles as lossp after k_gemm
    int*   counts = (int*)(ws + WS_COUNTS);
    ushort_t* xbf  = (ushort_t*)(out + O_XBF);
    ushort_t* cbbf = (ushort_t*)(out + O_CBBF);

    hipMemsetAsync(counts, 0, E_CODES * sizeof(int), stream);

    k_pack<<<2176, 256, 0, stream>>>(X, CB, xbf, cbbf);
    k_enorm<<<E_CODES, 64, 0, stream>>>(CB, enorm);
    k_gemm<<<512, 256, 0, stream>>>(xbf, cbbf, enorm, scores);
    // enorm's job is done; zero it and reuse as 512 loss partial slots
    hipMemsetAsync(enorm, 0, E_CODES * sizeof(float), stream);
    k_fused<<<B_ROWS / 4, 256, 0, stream>>>(X, CB, scores, counts, enorm, out);
    k_final<<<1, 512, 0, stream>>>(counts, enorm, out);
}

// Round 7
// 404.765 us; speedup vs baseline: 1.2761x; 1.0206x over previous
//
#include <hip/hip_runtime.h>
#include <stdint.h>

#define B_ROWS 8192
#define DIM 4096
#define E_CODES 512
#define MARGIN 16.0f

typedef __attribute__((ext_vector_type(8))) short short8;
typedef __attribute__((ext_vector_type(4))) float floatx4;
typedef __attribute__((ext_vector_type(4), aligned(4))) float f4u;  // unaligned-ok float4
typedef unsigned short ushort_t;

// ---- workspace layout (float units) ----
#define WS_SCORES 0                       // final scores: 8192*512 floats
#define WS_ENORM  4194304                 // 512 floats: ||e||^2 for k_gemm, then ZEROED and
                                          // reused as 512 loss partial-sum slots for k_fused
#define WS_COUNTS 4194816                 // 512 ints
#define WS_LOSS   4195328                 // (unused)

// ---- output layout (float units) ----
#define O_LOSS 0
#define O_Q    1
#define O_PERP 33554433
#define O_ENC  33554434
// scratch carved out of the Q region (fully overwritten by k_fused afterwards):
#define O_XBF   4          // bf16 X (swizzled): [4, 16777220)
#define O_CBBF  20971528   // bf16 CB (swizzled): [20971528, 22020104)

#define AS1 __attribute__((address_space(1)))
#define AS3 __attribute__((address_space(3)))

__device__ __forceinline__ void gld_lds16(const void* g, void* l) {
    // async global->LDS, 16B per lane; LDS dest = wave-uniform base + lane*16
    __builtin_amdgcn_global_load_lds((AS1 const void*)g, (AS3 void*)l, 16, 0, 0);
}

// pack two fp32 into (bf16(hi)<<16)|bf16(lo) by truncation — one v_perm_b32
__device__ inline uint32_t pk2(float hi, float lo) {
    return __builtin_amdgcn_perm(__float_as_uint(hi), __float_as_uint(lo), 0x07060302u);
}

// ---------------- codebook norms (fp32) ----------------
__global__ __launch_bounds__(64) void k_enorm(const float* __restrict__ cb, float* __restrict__ enorm) {
    const int e = blockIdx.x;
    const int lane = threadIdx.x;
    const float4* c4 = (const float4*)(cb + (size_t)e * DIM);
    float p = 0.f;
#pragma unroll
    for (int j = 0; j < 16; j++) {
        float4 v = c4[j * 64 + lane];
        p = fmaf(v.x, v.x, fmaf(v.y, v.y, fmaf(v.z, v.z, fmaf(v.w, v.w, p))));
    }
    for (int off = 32; off; off >>= 1) p += __shfl_down(p, off);
    if (lane == 0) enorm[e] = p;
}

// ---------------- bf16 pack with per-row XOR swizzle ----------------
// Within each 64-elem K-block, 16B-chunk c of row r is stored at chunk (c ^ (r&7)).
// Block-partitioned: blocks [0,2048) pack X (2048 chunks each), [2048,2176) pack CB.
__global__ __launch_bounds__(256) void k_pack(const float* __restrict__ X, const float* __restrict__ CB,
                                              ushort_t* __restrict__ xbf, ushort_t* __restrict__ cbbf) {
    const int b = blockIdx.x;
    const float* src;
    ushort_t* dst;
    int c0;
    if (b < 2048) { src = X;  dst = xbf;  c0 = b * 2048; }
    else          { src = CB; dst = cbbf; c0 = (b - 2048) * 2048; }
#pragma unroll
    for (int it = 0; it < 8; it++) {
        const int c = c0 + it * 256 + threadIdx.x;
        const int r = c >> 9, g = c & 511;
        const int gs = (g & ~7) | ((g & 7) ^ (r & 7));
        const float4* s4 = (const float4*)(src + ((size_t)c << 3));
        float4 v0 = s4[0], v1 = s4[1];
        *(uint4*)(dst + (size_t)r * DIM + gs * 8) =
            make_uint4(pk2(v0.y, v0.x), pk2(v0.w, v0.z), pk2(v1.y, v1.x), pk2(v1.w, v1.z));
    }
}

// ---------------- bf16 score GEMM: BM=64, BN=128, BK=64, counted-vmcnt 2-deep pipeline ------------
// 256 threads = 4 waves (2r x 2c); wave out = 32 rows x 64 cols (2x4 frags of 16x16x32).
// grid = 128 bm * 4 bn = 512 blocks = 2/CU (72 KiB LDS x 2 = 144 <= 160), 8 waves/CU.
// T4 pipeline: 3 LDS buffers, stage tile t+2 each iter, RAW s_barrier (no vmcnt(0) drain),
// s_waitcnt vmcnt(6) retires exactly tile t's 6 loads/wave; t+1,t+2's 12 stay in flight
// across the barrier. One barrier/iter: stage is issued AFTER the barrier, so the recycled
// buffer (read at t-1 by all waves) is provably free.
__global__ __launch_bounds__(256, 2) void k_gemm(const ushort_t* __restrict__ xbf, const ushort_t* __restrict__ cbbf,
                                                 const float* __restrict__ enorm, float* __restrict__ scores) {
    __shared__ __align__(16) ushort_t As[3 * 64 * 64];    // 3 x 8 KiB
    __shared__ __align__(16) ushort_t Bs[3 * 128 * 64];   // 3 x 16 KiB
    const int bid = blockIdx.x;
    const int bn = bid & 3;
    const int bm = bid >> 2;
    const int tid = threadIdx.x;
    const int lane = tid & 63;
    const int w = tid >> 6;
    const int wr = w >> 1, wc = w & 1;
    const int m16 = lane & 15, q4 = lane >> 4;

    const int srow = lane >> 3;
    const int scol = (lane & 7) * 8;
    const ushort_t* ax = xbf + (size_t)(bm * 64 + w * 8 + srow) * DIM + scol;
    const ushort_t* bx = cbbf + (size_t)(bn * 128 + w * 8 + srow) * DIM + scol;

    floatx4 acc[2][4];
#pragma unroll
    for (int i = 0; i < 2; i++)
#pragma unroll
        for (int j = 0; j < 4; j++) acc[i][j] = (floatx4){0.f, 0.f, 0.f, 0.f};

    const int kx = (m16 & 7) * 8;  // frag-read XOR key (ushort units)

    // 6 gld_lds per wave per tile (2 A + 4 B) -> vmcnt granularity of 6
#define STAGE(BUF, KT)                                                                      \
    {                                                                                       \
        ushort_t* asd = &As[(BUF) * 4096];                                                  \
        ushort_t* bsd = &Bs[(BUF) * 8192];                                                  \
        _Pragma("unroll")                                                                   \
        for (int j = 0; j < 2; j++)                                                         \
            gld_lds16(ax + (size_t)j * 32 * DIM + (KT), asd + (j * 32 + w * 8) * 64);       \
        _Pragma("unroll")                                                                   \
        for (int j = 0; j < 4; j++)                                                         \
            gld_lds16(bx + (size_t)j * 32 * DIM + (KT), bsd + (j * 32 + w * 8) * 64);       \
    }

    STAGE(0, 0)
    STAGE(1, 64)
    int b0 = 0, b1 = 1, b2 = 2;

    for (int t = 0; t < 64; ++t) {
        // retire tile t's own 6 loads; keep t+1/t+2's in flight (never drain to 0 mid-loop)
        if (t < 63) asm volatile("s_waitcnt vmcnt(6)" ::: "memory");
        else        asm volatile("s_waitcnt vmcnt(0)" ::: "memory");
        __builtin_amdgcn_s_barrier();        // raw barrier: no compiler-forced vmcnt(0) drain
        __builtin_amdgcn_sched_barrier(0);   // rule #18: pin ds_reads below the barrier

        if (t + 2 < 64) STAGE(b2, (t + 2) * 64)

        const ushort_t* Ab = &As[b0 * 4096];
        const ushort_t* Bb = &Bs[b0 * 8192];
#pragma unroll
        for (int kk = 0; kk < 2; kk++) {
            short8 a[2], b[4];
#pragma unroll
            for (int i = 0; i < 2; i++)
                a[i] = *(const short8*)(&Ab[(wr * 32 + i * 16 + m16) * 64 + ((kk * 32 + q4 * 8) ^ kx)]);
#pragma unroll
            for (int j = 0; j < 4; j++)
                b[j] = *(const short8*)(&Bb[(wc * 64 + j * 16 + m16) * 64 + ((kk * 32 + q4 * 8) ^ kx)]);
#pragma unroll
            for (int i = 0; i < 2; i++)
#pragma unroll
                for (int j = 0; j < 4; j++)
                    acc[i][j] = __builtin_amdgcn_mfma_f32_16x16x32_bf16(a[i], b[j], acc[i][j], 0, 0, 0);
        }
        __builtin_amdgcn_sched_barrier(0);   // keep this tile's ds_reads inside its phase
        const int tmp = b0; b0 = b1; b1 = b2; b2 = tmp;
    }
#undef STAGE

    // epilogue: score = ||e||^2 - 2*dot ; C/D layout: col=lane&15, row=(lane>>4)*4+rr
#pragma unroll
    for (int j = 0; j < 4; j++) {
        const int col = bn * 128 + wc * 64 + j * 16 + m16;
        const float en = enorm[col];
#pragma unroll
        for (int i = 0; i < 2; i++) {
            const int row0 = bm * 64 + wr * 32 + i * 16 + q4 * 4;
#pragma unroll
            for (int rr = 0; rr < 4; rr++)
                scores[(size_t)(row0 + rr) * E_CODES + col] = fmaf(-2.0f, acc[i][j][rr], en);
        }
    }
}

// ---------------- fused: argmin + (rare) exact refine + quantize + one-hot + loss ----------------
// Loss accumulation: per-wave butterfly (bitwise as before) -> per-block LDS reduce ->
// ONE atomicAdd per block into lossp[blockIdx&511] (~4 adds/slot). No same-address chain.
__global__ __launch_bounds__(256) void k_fused(const float* __restrict__ X, const float* __restrict__ CB,
                                               const float* __restrict__ scores,
                                               int* __restrict__ counts, float* __restrict__ lossp,
                                               float* __restrict__ out) {
    __shared__ float lred[4];
    const int tid = threadIdx.x;
    const int lane = tid & 63, w = tid >> 6;
    const int row = blockIdx.x * 4 + w;

    const float* sr = scores + (size_t)row * E_CODES;
    float s[8];
#pragma unroll
    for (int g = 0; g < 8; g++) s[g] = sr[g * 64 + lane];

    // wave argmin (approx scores), tie -> lower index
    float mv = s[0]; int mi = lane;
#pragma unroll
    for (int g = 1; g < 8; g++) { if (s[g] < mv) { mv = s[g]; mi = g * 64 + lane; } }
    for (int off = 32; off; off >>= 1) {
        float ov = __shfl_xor(mv, off); int oi = __shfl_xor(mi, off);
        if (ov < mv || (ov == mv && oi < mi)) { mv = ov; mi = oi; }
    }
    const float thr = mv + MARGIN;

    unsigned long long m0 = __ballot(s[0] <= thr), m1 = __ballot(s[1] <= thr);
    unsigned long long m2 = __ballot(s[2] <= thr), m3 = __ballot(s[3] <= thr);
    unsigned long long m4 = __ballot(s[4] <= thr), m5 = __ballot(s[5] <= thr);
    unsigned long long m6 = __ballot(s[6] <= thr), m7 = __ballot(s[7] <= thr);
    const int ncand = __popcll(m0) + __popcll(m1) + __popcll(m2) + __popcll(m3) +
                      __popcll(m4) + __popcll(m5) + __popcll(m6) + __popcll(m7);

    const float4* xr4 = (const float4*)(X + (size_t)row * DIM);
    int beste = mi;  // unique candidate == approx argmin

    if (ncand > 1) {
        // exact fp32 refine over margin candidates; butterfly sums bit-identical on all lanes
        float bestd = 3.0e38f; beste = 1 << 30;
#define REFINE_GROUP(MG, G)                                                                 \
        {                                                                                   \
            unsigned long long mask = (MG);                                                 \
            while (mask) {                                                                  \
                const int b = __builtin_ctzll(mask); mask &= mask - 1;                      \
                const int e = (G) * 64 + b;                                                 \
                const float4* cr4 = (const float4*)(CB + (size_t)e * DIM);                  \
                float p = 0.f;                                                              \
                _Pragma("unroll")                                                           \
                for (int i = 0; i < 16; i++) {                                              \
                    float4 c = cr4[i * 64 + lane];                                          \
                    float4 x = xr4[i * 64 + lane];                                          \
                    float dx = x.x - c.x, dy = x.y - c.y, dz = x.z - c.z, dw = x.w - c.w;   \
                    p = fmaf(dx, dx, fmaf(dy, dy, fmaf(dz, dz, fmaf(dw, dw, p))));          \
                }                                                                           \
                for (int off = 32; off; off >>= 1) p += __shfl_xor(p, off);                 \
                if (p < bestd || (p == bestd && e < beste)) { bestd = p; beste = e; }       \
            }                                                                               \
        }
        REFINE_GROUP(m0, 0) REFINE_GROUP(m1, 1) REFINE_GROUP(m2, 2) REFINE_GROUP(m3, 3)
        REFINE_GROUP(m4, 4) REFINE_GROUP(m5, 5) REFINE_GROUP(m6, 6) REFINE_GROUP(m7, 7)
#undef REFINE_GROUP
    }

    // quantized_st = x + (q - x); loss fma-nest i=0..15 + butterfly (bitwise same as baseline).
    const float4* cq4 = (const float4*)(CB + (size_t)beste * DIM);
    f4u* oq4 = (f4u*)(out + O_Q + (size_t)row * DIM);   // out+1 is only 4B-aligned

#define LD(K) float4 x##K = xr4[(K) * 64 + lane]; float4 q##K = cq4[(K) * 64 + lane];
    LD(0) LD(1) LD(2) LD(3) LD(4) LD(5) LD(6) LD(7)
    LD(8) LD(9) LD(10) LD(11) LD(12) LD(13) LD(14) LD(15)
#undef LD
    float p = 0.f;
#define ST(K)                                                                               \
    {                                                                                       \
        float dx = q##K.x - x##K.x, dy = q##K.y - x##K.y;                                   \
        float dz = q##K.z - x##K.z, dw = q##K.w - x##K.w;                                   \
        p = fmaf(dx, dx, fmaf(dy, dy, fmaf(dz, dz, fmaf(dw, dw, p))));                      \
        f4u r;                                                                              \
        r.x = x##K.x + dx; r.y = x##K.y + dy; r.z = x##K.z + dz; r.w = x##K.w + dw;         \
        oq4[(K) * 64 + lane] = r;                                                           \
    }
    ST(0) ST(1) ST(2) ST(3) ST(4) ST(5) ST(6) ST(7)
    ST(8) ST(9) ST(10) ST(11) ST(12) ST(13) ST(14) ST(15)
#undef ST
    for (int off = 32; off; off >>= 1) p += __shfl_xor(p, off);

    // one-hot row (O_ENC is 8B-aligned -> float2)
    float2* oe2 = (float2*)(out + O_ENC + (size_t)row * E_CODES);
#pragma unroll
    for (int k = 0; k < 4; k++) {
        const int e0 = (k * 64 + lane) * 2;
        float2 v; v.x = (e0 == beste) ? 1.0f : 0.0f; v.y = (e0 + 1 == beste) ? 1.0f : 0.0f;
        oe2[k * 64 + lane] = v;
    }

    // loss: block-level reduce, single spread-slot atomic per block (kills the 8192-deep
    // same-address atomic chain that serialized every previous streaming kernel).
    if (lane == 0) {
        lred[w] = p;
        atomicAdd(&counts[beste], 1);   // 512 spread addresses — cheap
    }
    __syncthreads();
    if (tid == 0) {
        float P = ((lred[0] + lred[1]) + lred[2]) + lred[3];
        atomicAdd(&lossp[blockIdx.x & 511], P);
    }
}

// ---------------- loss + perplexity ----------------
__global__ __launch_bounds__(512) void k_final(const int* __restrict__ counts, const float* __restrict__ lossp,
                                               float* __restrict__ out) {
    const int tid = threadIdx.x;
    const int lane = tid & 63, w = tid >> 6;
    __shared__ float r[8];
    __shared__ float r2[8];
    const float p = (float)counts[tid] * (1.0f / 8192.0f);
    float h = p * logf(p + 1e-10f);
    float l = lossp[tid];
    for (int off = 32; off; off >>= 1) { h += __shfl_down(h, off); l += __shfl_down(l, off); }
    if (lane == 0) { r[w] = h; r2[w] = l; }
    __syncthreads();
    if (tid == 0) {
        float H = 0.f, L = 0.f;
        for (int k = 0; k < 8; k++) { H += r[k]; L += r2[k]; }
        out[O_PERP] = expf(-H);
        out[O_LOSS] = L * (1.25f / 33554432.0f);  // q_latent + 0.25*e_latent = 1.25*MSE
    }
}

extern "C" void kernel_launch(void* const* d_in, const int* in_sizes, int n_in,
                              void* d_out, int out_size, void* d_ws, size_t ws_size,
                              hipStream_t stream) {
    const float* X  = (const float*)d_in[0];   // inputs  [8192, 8,8,8,8] -> [8192,4096]
    const float* CB = (const float*)d_in[1];   // codebook [512, 4096]
    float* out = (float*)d_out;
    float* ws  = (float*)d_ws;
    float* scores = ws + WS_SCORES;
    float* enorm  = ws + WS_ENORM;   // doubles as lossp after k_gemm
    int*   counts = (int*)(ws + WS_COUNTS);
    ushort_t* xbf  = (ushort_t*)(out + O_XBF);
    ushort_t* cbbf = (ushort_t*)(out + O_CBBF);

    hipMemsetAsync(counts, 0, E_CODES * sizeof(int), stream);

    k_pack<<<2176, 256, 0, stream>>>(X, CB, xbf, cbbf);
    k_enorm<<<E_CODES, 64, 0, stream>>>(CB, enorm);
    k_gemm<<<512, 256, 0, stream>>>(xbf, cbbf, enorm, scores);
    // enorm's job is done; zero it and reuse as 512 loss partial slots
    hipMemsetAsync(enorm, 0, E_CODES * sizeof(float), stream);
    k_fused<<<B_ROWS / 4, 256, 0, stream>>>(X, CB, scores, counts, enorm, out);
    k_final<<<1, 512, 0, stream>>>(counts, enorm, out);
}

// Round 8
// 380.398 us; speedup vs baseline: 1.3578x; 1.0641x over previous
//
#include <hip/hip_runtime.h>
#include <stdint.h>

#define B_ROWS 8192
#define DIM 4096
#define E_CODES 512
#define MARGIN 16.0f

typedef __attribute__((ext_vector_type(8))) short short8;
typedef __attribute__((ext_vector_type(4))) float floatx4;
typedef __attribute__((ext_vector_type(4), aligned(4))) float f4u;  // unaligned-ok float4
typedef unsigned short ushort_t;

// ---- workspace layout (float units) ----
#define WS_SCORES 0                       // final scores: 8192*512 floats
#define WS_ENORM  4194304                 // 512 floats: ||e||^2 for k_gemm, then ZEROED and
                                          // reused as 512 loss partial-sum slots for k_fused
#define WS_COUNTS 4194816                 // 512 ints
#define WS_LOSS   4195328                 // (unused)

// ---- output layout (float units) ----
#define O_LOSS 0
#define O_Q    1
#define O_PERP 33554433
#define O_ENC  33554434
// scratch carved out of the Q region (fully overwritten by k_fused afterwards):
#define O_XBF   4          // bf16 X (swizzled): [4, 16777220)
#define O_CBBF  20971528   // bf16 CB (swizzled): [20971528, 22020104)

#define AS1 __attribute__((address_space(1)))
#define AS3 __attribute__((address_space(3)))

__device__ __forceinline__ void gld_lds16(const void* g, void* l) {
    // async global->LDS, 16B per lane; LDS dest = wave-uniform base + lane*16
    __builtin_amdgcn_global_load_lds((AS1 const void*)g, (AS3 void*)l, 16, 0, 0);
}

// pack two fp32 into (bf16(hi)<<16)|bf16(lo) by truncation — one v_perm_b32
__device__ inline uint32_t pk2(float hi, float lo) {
    return __builtin_amdgcn_perm(__float_as_uint(hi), __float_as_uint(lo), 0x07060302u);
}

// ---------------- codebook norms (fp32) ----------------
__global__ __launch_bounds__(64) void k_enorm(const float* __restrict__ cb, float* __restrict__ enorm) {
    const int e = blockIdx.x;
    const int lane = threadIdx.x;
    const float4* c4 = (const float4*)(cb + (size_t)e * DIM);
    float p = 0.f;
#pragma unroll
    for (int j = 0; j < 16; j++) {
        float4 v = c4[j * 64 + lane];
        p = fmaf(v.x, v.x, fmaf(v.y, v.y, fmaf(v.z, v.z, fmaf(v.w, v.w, p))));
    }
    for (int off = 32; off; off >>= 1) p += __shfl_down(p, off);
    if (lane == 0) enorm[e] = p;
}

// ---------------- bf16 pack with per-row XOR swizzle ----------------
// Within each 64-elem K-block, 16B-chunk c of row r is stored at chunk (c ^ (r&7)).
// Block-partitioned: blocks [0,2048) pack X (2048 chunks each), [2048,2176) pack CB.
__global__ __launch_bounds__(256) void k_pack(const float* __restrict__ X, const float* __restrict__ CB,
                                              ushort_t* __restrict__ xbf, ushort_t* __restrict__ cbbf) {
    const int b = blockIdx.x;
    const float* src;
    ushort_t* dst;
    int c0;
    if (b < 2048) { src = X;  dst = xbf;  c0 = b * 2048; }
    else          { src = CB; dst = cbbf; c0 = (b - 2048) * 2048; }
#pragma unroll
    for (int it = 0; it < 8; it++) {
        const int c = c0 + it * 256 + threadIdx.x;
        const int r = c >> 9, g = c & 511;
        const int gs = (g & ~7) | ((g & 7) ^ (r & 7));
        const float4* s4 = (const float4*)(src + ((size_t)c << 3));
        float4 v0 = s4[0], v1 = s4[1];
        *(uint4*)(dst + (size_t)r * DIM + gs * 8) =
            make_uint4(pk2(v0.y, v0.x), pk2(v0.w, v0.z), pk2(v1.y, v1.x), pk2(v1.w, v1.z));
    }
}

// ---------------- bf16 score GEMM: BM=64, BN=128, BK=64, counted-vmcnt 2-deep pipeline ------------
// (unchanged from round 7 — measured ~8 µs better than the drain-0 version)
__global__ __launch_bounds__(256, 2) void k_gemm(const ushort_t* __restrict__ xbf, const ushort_t* __restrict__ cbbf,
                                                 const float* __restrict__ enorm, float* __restrict__ scores) {
    __shared__ __align__(16) ushort_t As[3 * 64 * 64];    // 3 x 8 KiB
    __shared__ __align__(16) ushort_t Bs[3 * 128 * 64];   // 3 x 16 KiB
    const int bid = blockIdx.x;
    const int bn = bid & 3;
    const int bm = bid >> 2;
    const int tid = threadIdx.x;
    const int lane = tid & 63;
    const int w = tid >> 6;
    const int wr = w >> 1, wc = w & 1;
    const int m16 = lane & 15, q4 = lane >> 4;

    const int srow = lane >> 3;
    const int scol = (lane & 7) * 8;
    const ushort_t* ax = xbf + (size_t)(bm * 64 + w * 8 + srow) * DIM + scol;
    const ushort_t* bx = cbbf + (size_t)(bn * 128 + w * 8 + srow) * DIM + scol;

    floatx4 acc[2][4];
#pragma unroll
    for (int i = 0; i < 2; i++)
#pragma unroll
        for (int j = 0; j < 4; j++) acc[i][j] = (floatx4){0.f, 0.f, 0.f, 0.f};

    const int kx = (m16 & 7) * 8;  // frag-read XOR key (ushort units)

    // 6 gld_lds per wave per tile (2 A + 4 B) -> vmcnt granularity of 6
#define STAGE(BUF, KT)                                                                      \
    {                                                                                       \
        ushort_t* asd = &As[(BUF) * 4096];                                                  \
        ushort_t* bsd = &Bs[(BUF) * 8192];                                                  \
        _Pragma("unroll")                                                                   \
        for (int j = 0; j < 2; j++)                                                         \
            gld_lds16(ax + (size_t)j * 32 * DIM + (KT), asd + (j * 32 + w * 8) * 64);       \
        _Pragma("unroll")                                                                   \
        for (int j = 0; j < 4; j++)                                                         \
            gld_lds16(bx + (size_t)j * 32 * DIM + (KT), bsd + (j * 32 + w * 8) * 64);       \
    }

    STAGE(0, 0)
    STAGE(1, 64)
    int b0 = 0, b1 = 1, b2 = 2;

    for (int t = 0; t < 64; ++t) {
        // retire tile t's own 6 loads; keep t+1/t+2's in flight (never drain to 0 mid-loop)
        if (t < 63) asm volatile("s_waitcnt vmcnt(6)" ::: "memory");
        else        asm volatile("s_waitcnt vmcnt(0)" ::: "memory");
        __builtin_amdgcn_s_barrier();        // raw barrier: no compiler-forced vmcnt(0) drain
        __builtin_amdgcn_sched_barrier(0);   // rule #18: pin ds_reads below the barrier

        if (t + 2 < 64) STAGE(b2, (t + 2) * 64)

        const ushort_t* Ab = &As[b0 * 4096];
        const ushort_t* Bb = &Bs[b0 * 8192];
#pragma unroll
        for (int kk = 0; kk < 2; kk++) {
            short8 a[2], b[4];
#pragma unroll
            for (int i = 0; i < 2; i++)
                a[i] = *(const short8*)(&Ab[(wr * 32 + i * 16 + m16) * 64 + ((kk * 32 + q4 * 8) ^ kx)]);
#pragma unroll
            for (int j = 0; j < 4; j++)
                b[j] = *(const short8*)(&Bb[(wc * 64 + j * 16 + m16) * 64 + ((kk * 32 + q4 * 8) ^ kx)]);
#pragma unroll
            for (int i = 0; i < 2; i++)
#pragma unroll
                for (int j = 0; j < 4; j++)
                    acc[i][j] = __builtin_amdgcn_mfma_f32_16x16x32_bf16(a[i], b[j], acc[i][j], 0, 0, 0);
        }
        __builtin_amdgcn_sched_barrier(0);   // keep this tile's ds_reads inside its phase
        const int tmp = b0; b0 = b1; b1 = b2; b2 = tmp;
    }
#undef STAGE

    // epilogue: score = ||e||^2 - 2*dot ; C/D layout: col=lane&15, row=(lane>>4)*4+rr
#pragma unroll
    for (int j = 0; j < 4; j++) {
        const int col = bn * 128 + wc * 64 + j * 16 + m16;
        const float en = enorm[col];
#pragma unroll
        for (int i = 0; i < 2; i++) {
            const int row0 = bm * 64 + wr * 32 + i * 16 + q4 * 4;
#pragma unroll
            for (int rr = 0; rr < 4; rr++)
                scores[(size_t)(row0 + rr) * E_CODES + col] = fmaf(-2.0f, acc[i][j][rr], en);
        }
    }
}

// ---------------- fused: argmin + (rare) exact refine + quantize + one-hot + loss ----------------
// NEW: X-row prefetch issued BEFORE the argmin phase and pinned with sched_barrier(0) so the
// ~900-cycle HBM latency of the 16 float4 X loads hides under score-load + argmin + ballots.
// (Round-5 attempt failed because the compiler sank the loads; the fence is the fix.)
__global__ __launch_bounds__(256) void k_fused(const float* __restrict__ X, const float* __restrict__ CB,
                                               const float* __restrict__ scores,
                                               int* __restrict__ counts, float* __restrict__ lossp,
                                               float* __restrict__ out) {
    __shared__ float lred[4];
    const int tid = threadIdx.x;
    const int lane = tid & 63, w = tid >> 6;
    const int row = blockIdx.x * 4 + w;

    // phase 0a: issue score loads
    const float* sr = scores + (size_t)row * E_CODES;
    float s[8];
#pragma unroll
    for (int g = 0; g < 8; g++) s[g] = sr[g * 64 + lane];
    __builtin_amdgcn_sched_barrier(0);   // scores issued first (argmin waits only on these)

    // phase 0b: issue the full X row as 16 named float4 loads — independent of argmin
    const float4* xr4 = (const float4*)(X + (size_t)row * DIM);
#define LDX(K) float4 x##K = xr4[(K) * 64 + lane];
    LDX(0) LDX(1) LDX(2) LDX(3) LDX(4) LDX(5) LDX(6) LDX(7)
    LDX(8) LDX(9) LDX(10) LDX(11) LDX(12) LDX(13) LDX(14) LDX(15)
#undef LDX
    __builtin_amdgcn_sched_barrier(0);   // pin: X loads may NOT sink below this point

    // phase 1: wave argmin (approx scores), tie -> lower index
    float mv = s[0]; int mi = lane;
#pragma unroll
    for (int g = 1; g < 8; g++) { if (s[g] < mv) { mv = s[g]; mi = g * 64 + lane; } }
    for (int off = 32; off; off >>= 1) {
        float ov = __shfl_xor(mv, off); int oi = __shfl_xor(mi, off);
        if (ov < mv || (ov == mv && oi < mi)) { mv = ov; mi = oi; }
    }
    const float thr = mv + MARGIN;

    unsigned long long m0 = __ballot(s[0] <= thr), m1 = __ballot(s[1] <= thr);
    unsigned long long m2 = __ballot(s[2] <= thr), m3 = __ballot(s[3] <= thr);
    unsigned long long m4 = __ballot(s[4] <= thr), m5 = __ballot(s[5] <= thr);
    unsigned long long m6 = __ballot(s[6] <= thr), m7 = __ballot(s[7] <= thr);
    const int ncand = __popcll(m0) + __popcll(m1) + __popcll(m2) + __popcll(m3) +
                      __popcll(m4) + __popcll(m5) + __popcll(m6) + __popcll(m7);

    int beste = mi;  // unique candidate == approx argmin

    if (ncand > 1) {
        // exact fp32 refine over margin candidates; butterfly sums bit-identical on all lanes
        // (reads xr4 directly — rare path, keeps the exact baseline fma nest)
        float bestd = 3.0e38f; beste = 1 << 30;
#define REFINE_GROUP(MG, G)                                                                 \
        {                                                                                   \
            unsigned long long mask = (MG);                                                 \
            while (mask) {                                                                  \
                const int b = __builtin_ctzll(mask); mask &= mask - 1;                      \
                const int e = (G) * 64 + b;                                                 \
                const float4* cr4 = (const float4*)(CB + (size_t)e * DIM);                  \
                float p = 0.f;                                                              \
                _Pragma("unroll")                                                           \
                for (int i = 0; i < 16; i++) {                                              \
                    float4 c = cr4[i * 64 + lane];                                          \
                    float4 x = xr4[i * 64 + lane];                                          \
                    float dx = x.x - c.x, dy = x.y - c.y, dz = x.z - c.z, dw = x.w - c.w;   \
                    p = fmaf(dx, dx, fmaf(dy, dy, fmaf(dz, dz, fmaf(dw, dw, p))));          \
                }                                                                           \
                for (int off = 32; off; off >>= 1) p += __shfl_xor(p, off);                 \
                if (p < bestd || (p == bestd && e < beste)) { bestd = p; beste = e; }       \
            }                                                                               \
        }
        REFINE_GROUP(m0, 0) REFINE_GROUP(m1, 1) REFINE_GROUP(m2, 2) REFINE_GROUP(m3, 3)
        REFINE_GROUP(m4, 4) REFINE_GROUP(m5, 5) REFINE_GROUP(m6, 6) REFINE_GROUP(m7, 7)
#undef REFINE_GROUP
    }

    // phase 2: quantized_st = x + (q - x); loss fma-nest i=0..15 + butterfly (bitwise as before).
    const float4* cq4 = (const float4*)(CB + (size_t)beste * DIM);
    f4u* oq4 = (f4u*)(out + O_Q + (size_t)row * DIM);   // out+1 is only 4B-aligned

#define LDQ(K) float4 q##K = cq4[(K) * 64 + lane];
    LDQ(0) LDQ(1) LDQ(2) LDQ(3) LDQ(4) LDQ(5) LDQ(6) LDQ(7)
    LDQ(8) LDQ(9) LDQ(10) LDQ(11) LDQ(12) LDQ(13) LDQ(14) LDQ(15)
#undef LDQ
    float p = 0.f;
#define ST(K)                                                                               \
    {                                                                                       \
        float dx = q##K.x - x##K.x, dy = q##K.y - x##K.y;                                   \
        float dz = q##K.z - x##K.z, dw = q##K.w - x##K.w;                                   \
        p = fmaf(dx, dx, fmaf(dy, dy, fmaf(dz, dz, fmaf(dw, dw, p))));                      \
        f4u r;                                                                              \
        r.x = x##K.x + dx; r.y = x##K.y + dy; r.z = x##K.z + dz; r.w = x##K.w + dw;         \
        oq4[(K) * 64 + lane] = r;                                                           \
    }
    ST(0) ST(1) ST(2) ST(3) ST(4) ST(5) ST(6) ST(7)
    ST(8) ST(9) ST(10) ST(11) ST(12) ST(13) ST(14) ST(15)
#undef ST
    for (int off = 32; off; off >>= 1) p += __shfl_xor(p, off);

    // one-hot row (O_ENC is 8B-aligned -> float2)
    float2* oe2 = (float2*)(out + O_ENC + (size_t)row * E_CODES);
#pragma unroll
    for (int k = 0; k < 4; k++) {
        const int e0 = (k * 64 + lane) * 2;
        float2 v; v.x = (e0 == beste) ? 1.0f : 0.0f; v.y = (e0 + 1 == beste) ? 1.0f : 0.0f;
        oe2[k * 64 + lane] = v;
    }

    // loss: block-level reduce, single spread-slot atomic per block
    if (lane == 0) {
        lred[w] = p;
        atomicAdd(&counts[beste], 1);   // 512 spread addresses — cheap
    }
    __syncthreads();
    if (tid == 0) {
        float P = ((lred[0] + lred[1]) + lred[2]) + lred[3];
        atomicAdd(&lossp[blockIdx.x & 511], P);
    }
}

// ---------------- loss + perplexity ----------------
__global__ __launch_bounds__(512) void k_final(const int* __restrict__ counts, const float* __restrict__ lossp,
                                               float* __restrict__ out) {
    const int tid = threadIdx.x;
    const int lane = tid & 63, w = tid >> 6;
    __shared__ float r[8];
    __shared__ float r2[8];
    const float p = (float)counts[tid] * (1.0f / 8192.0f);
    float h = p * logf(p + 1e-10f);
    float l = lossp[tid];
    for (int off = 32; off; off >>= 1) { h += __shfl_down(h, off); l += __shfl_down(l, off); }
    if (lane == 0) { r[w] = h; r2[w] = l; }
    __syncthreads();
    if (tid == 0) {
        float H = 0.f, L = 0.f;
        for (int k = 0; k < 8; k++) { H += r[k]; L += r2[k]; }
        out[O_PERP] = expf(-H);
        out[O_LOSS] = L * (1.25f / 33554432.0f);  // q_latent + 0.25*e_latent = 1.25*MSE
    }
}

extern "C" void kernel_launch(void* const* d_in, const int* in_sizes, int n_in,
                              void* d_out, int out_size, void* d_ws, size_t ws_size,
                              hipStream_t stream) {
    const float* X  = (const float*)d_in[0];   // inputs  [8192, 8,8,8,8] -> [8192,4096]
    const float* CB = (const float*)d_in[1];   // codebook [512, 4096]
    float* out = (float*)d_out;
    float* ws  = (float*)d_ws;
    float* scores = ws + WS_SCORES;
    float* enorm  = ws + WS_ENORM;   // doubles as lossp after k_gemm
    int*   counts = (int*)(ws + WS_COUNTS);
    ushort_t* xbf  = (ushort_t*)(out + O_XBF);
    ushort_t* cbbf = (ushort_t*)(out + O_CBBF);

    hipMemsetAsync(counts, 0, E_CODES * sizeof(int), stream);

    k_pack<<<2176, 256, 0, stream>>>(X, CB, xbf, cbbf);
    k_enorm<<<E_CODES, 64, 0, stream>>>(CB, enorm);
    k_gemm<<<512, 256, 0, stream>>>(xbf, cbbf, enorm, scores);
    // enorm's job is done; zero it and reuse as 512 loss partial slots
    hipMemsetAsync(enorm, 0, E_CODES * sizeof(float), stream);
    k_fused<<<B_ROWS / 4, 256, 0, stream>>>(X, CB, scores, counts, enorm, out);
    k_final<<<1, 512, 0, stream>>>(counts, enorm, out);
}